// Round 4
// baseline (20.080 us; speedup 1.0000x reference)
//
#include <hip/hip_runtime.h>
#include <math.h>

// out[b,c] = sum_n exp(-2*r2(n,b)) * exp(-max(t,0)/2) * mem[n,c]
// Tube-culled: arg = -2*r2 - max(t,0)/2; drop arg < -20 (exp(-20) ~ 2e-9).
// March the dominant axis; per integer plane the relevant cross-section has
// in-plane radius <= 3.17/|d_a| <= 3.17*sqrt(3) ~ 5.5 (+1 rounding) -> a
// 16x16 box centered on the line crossing covers it. Planes with tk > 46
// culled (inside the box t >= tk - 7.5 > 38.5 -> arg < -20 up to ~2e-9).
//
// Structure: ONE graph node. 32 blocks (one per ray) x 1024 threads
// (4 planes in flight x 16x16 box). Each block writes its own out[b][0..16)
// with plain stores -> no memset, no atomics, no reduce kernel.

constexpr int BRAYS = 32;
constexpr int DGRID = 128;
constexpr int NTHR  = 1024;
constexpr int WPB   = 4;               // planes in flight per block
constexpr int ITERS = DGRID / WPB;     // 32

__global__ __launch_bounds__(NTHR)
void hpm_ray(const float* __restrict__ ray_o,
             const float* __restrict__ ray_d,
             const float* __restrict__ mem,
             float* __restrict__ out)
{
    const int tid = threadIdx.x;
    const int b   = blockIdx.x;

    // ---- ray setup (block-uniform) ----
    const float ox = ray_o[b*3+0], oy = ray_o[b*3+1], oz = ray_o[b*3+2];
    const float dx = ray_d[b*3+0], dy = ray_d[b*3+1], dz = ray_d[b*3+2];
    const float ax = fabsf(dx), ay = fabsf(dy), az = fabsf(dz);

    int a;                                   // dominant axis
    if (ax >= ay && ax >= az) a = 0; else if (ay >= az) a = 1; else a = 2;
    const int p1 = (a == 0) ? 1 : 0;
    const int p2 = (a == 2) ? 1 : 2;

    const float o3[3] = {ox, oy, oz};
    const float d3[3] = {dx, dy, dz};
    const int   st[3] = {DGRID * DGRID * 16, DGRID * 16, 16};  // float strides

    const float oa = o3[a],  da = d3[a];
    const float o1 = o3[p1], d1 = d3[p1];
    const float o2 = o3[p2], d2 = d3[p2];
    const int   sa = st[a],  s1 = st[p1], s2 = st[p2];
    const float inv_da = 1.0f / da;
    const float q = 2.0f - (dx*dx + dy*dy + dz*dz);   // r2 = |e|^2 - q*t^2

    // ---- thread mapping: 4 plane slots x 16x16 in-plane box ----
    const int w = tid >> 8;          // plane sub-slot 0..3 (wave-uniform)
    const int p = tid & 255;
    const int u = p >> 4;            // 0..15 along p1
    const int v = p & 15;            // 0..15 along p2

    float acc[16];
    #pragma unroll
    for (int c = 0; c < 16; ++c) acc[c] = 0.0f;

    #pragma unroll 4
    for (int i = 0; i < ITERS; ++i) {
        const int   k  = i * WPB + w;
        const float tk = ((float)k - oa) * inv_da;     // t at plane crossing
        if (tk > 46.0f) continue;                      // wave-uniform cull

        const float yc = o1 + tk * d1;
        const float zc = o2 + tk * d2;
        const int y = (int)floorf(yc) - 7 + u;
        const int z = (int)floorf(zc) - 7 + v;

        const float e0 = (float)k - oa;
        const float e1 = (float)y - o1;
        const float e2 = (float)z - o2;
        const float t   = fmaf(e0, da, fmaf(e1, d1, e2 * d2));
        const float ee  = fmaf(e0, e0, fmaf(e1, e1, e2 * e2));
        const float r2  = fmaf(-q * t, t, ee);
        const float arg = fmaf(fmaxf(t, 0.0f), -0.5f, -2.0f * r2);

        if (arg > -20.0f && ((unsigned)y < 128u) && ((unsigned)z < 128u)) {
            const float wgt = __expf(arg);
            const float4* row = reinterpret_cast<const float4*>(
                mem + (size_t)k * sa + (size_t)y * s1 + (size_t)z * s2);
            const float4 m0 = row[0], m1 = row[1], m2 = row[2], m3 = row[3];
            acc[ 0] = fmaf(wgt, m0.x, acc[ 0]); acc[ 1] = fmaf(wgt, m0.y, acc[ 1]);
            acc[ 2] = fmaf(wgt, m0.z, acc[ 2]); acc[ 3] = fmaf(wgt, m0.w, acc[ 3]);
            acc[ 4] = fmaf(wgt, m1.x, acc[ 4]); acc[ 5] = fmaf(wgt, m1.y, acc[ 5]);
            acc[ 6] = fmaf(wgt, m1.z, acc[ 6]); acc[ 7] = fmaf(wgt, m1.w, acc[ 7]);
            acc[ 8] = fmaf(wgt, m2.x, acc[ 8]); acc[ 9] = fmaf(wgt, m2.y, acc[ 9]);
            acc[10] = fmaf(wgt, m2.z, acc[10]); acc[11] = fmaf(wgt, m2.w, acc[11]);
            acc[12] = fmaf(wgt, m3.x, acc[12]); acc[13] = fmaf(wgt, m3.y, acc[13]);
            acc[14] = fmaf(wgt, m3.z, acc[14]); acc[15] = fmaf(wgt, m3.w, acc[15]);
        }
    }

    // ---- wave fold-reduction: halve register count each step ----
    // Final: lane<16 holds channel brev4(lane) summed over its 64 lanes.
    const int lane = tid & 63;
    float r[16];
    #pragma unroll
    for (int c = 0; c < 16; ++c) r[c] = acc[c];

#define FOLD(MASK, HALF)                                        \
    {                                                           \
        const bool hi = (lane & (MASK)) != 0;                   \
        _Pragma("unroll")                                       \
        for (int i = 0; i < (HALF); ++i) {                      \
            const float give = hi ? r[i] : r[i + (HALF)];       \
            const float keep = hi ? r[i + (HALF)] : r[i];       \
            r[i] = keep + __shfl_xor(give, (MASK), 64);         \
        }                                                       \
    }
    FOLD(1, 8)
    FOLD(2, 4)
    FOLD(4, 2)
    FOLD(8, 1)
#undef FOLD
    float sum = r[0];
    sum += __shfl_xor(sum, 16, 64);
    sum += __shfl_xor(sum, 32, 64);
    const int l4 = lane & 15;
    const int ch = ((l4 & 1) << 3) | ((l4 & 2) << 1) | ((l4 & 4) >> 1) | ((l4 & 8) >> 3);

    // ---- cross-wave combine (16 waves) + direct store ----
    __shared__ float ws[16][16];
    if (lane < 16) ws[tid >> 6][ch] = sum;
    __syncthreads();

    if (tid < 16) {
        float s = 0.0f;
        #pragma unroll
        for (int qw = 0; qw < 16; ++qw) s += ws[qw][tid];
        out[b * 16 + tid] = s;
    }
}

extern "C" void kernel_launch(void* const* d_in, const int* in_sizes, int n_in,
                              void* d_out, int out_size, void* d_ws, size_t ws_size,
                              hipStream_t stream)
{
    const float* ray_o = (const float*)d_in[0];   // [32,3]
    const float* ray_d = (const float*)d_in[1];   // [32,3]
    const float* mem   = (const float*)d_in[2];   // [128^3,16]
    float* out = (float*)d_out;                   // [32,16]

    hipLaunchKernelGGL(hpm_ray, dim3(BRAYS), dim3(NTHR), 0, stream,
                       ray_o, ray_d, mem, out);
}

// Round 5
// 12.085 us; speedup vs baseline: 1.6616x; 1.6616x over previous
//
#include <hip/hip_runtime.h>
#include <math.h>

// out[b,c] = sum_n exp(-2*r2(n,b)) * exp(-max(t,0)/2) * mem[n,c]
// Tube-culled: arg = -2*r2 - max(t,0)/2; drop arg < -20 (exp(-20) ~ 2e-9).
// March the dominant axis; per integer plane the relevant cross-section has
// in-plane radius <= 3.17/|d_a| <= 3.17*sqrt(3) ~ 5.5 (+1 rounding) -> a
// 16x16 box centered on the line crossing covers it. Planes with tk > 46
// culled (inside the box t >= tk - 7.5 > 38.5 -> arg < -20).
//
// Structure (R3-proven): 1024 blocks x 256 thr, 4 planes/block, wave
// fold-reduction, partials to d_ws; tiny 512-thread reduce kernel.
// ~10 us of the measured time is graph-replay/dispatch floor.

constexpr int BRAYS  = 32;
constexpr int DGRID  = 128;
constexpr int NCHUNK = 32;                 // plane-chunks per ray
constexpr int PLANES = DGRID / NCHUNK;     // 4 planes per block
constexpr int NTHR   = 256;
constexpr int NBLK   = BRAYS * NCHUNK;     // 1024 blocks

__global__ __launch_bounds__(NTHR)
void hpm_tube(const float* __restrict__ ray_o,
              const float* __restrict__ ray_d,
              const float* __restrict__ mem,
              float* __restrict__ part)   // [NCHUNK][BRAYS][16]
{
    const int tid   = threadIdx.x;
    const int b     = blockIdx.x & (BRAYS - 1);
    const int chunk = blockIdx.x >> 5;
    const int k0    = chunk * PLANES;

    // ---- ray setup (block-uniform) ----
    const float ox = ray_o[b*3+0], oy = ray_o[b*3+1], oz = ray_o[b*3+2];
    const float dx = ray_d[b*3+0], dy = ray_d[b*3+1], dz = ray_d[b*3+2];
    const float ax = fabsf(dx), ay = fabsf(dy), az = fabsf(dz);

    int a;                                   // dominant axis
    if (ax >= ay && ax >= az) a = 0; else if (ay >= az) a = 1; else a = 2;
    const int p1 = (a == 0) ? 1 : 0;
    const int p2 = (a == 2) ? 1 : 2;

    const float o3[3] = {ox, oy, oz};
    const float d3[3] = {dx, dy, dz};
    const int   st[3] = {DGRID * DGRID * 16, DGRID * 16, 16};  // float strides

    const float oa = o3[a],  da = d3[a];
    const float o1 = o3[p1], d1 = d3[p1];
    const float o2 = o3[p2], d2 = d3[p2];
    const int   sa = st[a],  s1 = st[p1], s2 = st[p2];
    const float inv_da = 1.0f / da;
    const float q = 2.0f - (dx*dx + dy*dy + dz*dz);   // r2 = |e|^2 - q*t^2

    // ---- thread's in-plane box offset ----
    const int u = tid >> 4;    // 0..15 along p1
    const int v = tid & 15;    // 0..15 along p2

    float acc[16];
    #pragma unroll
    for (int c = 0; c < 16; ++c) acc[c] = 0.0f;

    #pragma unroll
    for (int i = 0; i < PLANES; ++i) {
        const int   k  = k0 + i;
        const float tk = ((float)k - oa) * inv_da;     // t at plane crossing
        if (tk > 46.0f) continue;                      // forward decay cull

        const float yc = o1 + tk * d1;
        const float zc = o2 + tk * d2;
        const int y = (int)floorf(yc) - 7 + u;
        const int z = (int)floorf(zc) - 7 + v;

        const float e0 = (float)k - oa;
        const float e1 = (float)y - o1;
        const float e2 = (float)z - o2;
        const float t   = fmaf(e0, da, fmaf(e1, d1, e2 * d2));
        const float ee  = fmaf(e0, e0, fmaf(e1, e1, e2 * e2));
        const float r2  = fmaf(-q * t, t, ee);
        const float arg = fmaf(fmaxf(t, 0.0f), -0.5f, -2.0f * r2);

        if (arg > -20.0f && ((unsigned)y < 128u) && ((unsigned)z < 128u)) {
            const float w = __expf(arg);
            const float4* row = reinterpret_cast<const float4*>(
                mem + (size_t)k * sa + (size_t)y * s1 + (size_t)z * s2);
            const float4 m0 = row[0], m1 = row[1], m2 = row[2], m3 = row[3];
            acc[ 0] = fmaf(w, m0.x, acc[ 0]); acc[ 1] = fmaf(w, m0.y, acc[ 1]);
            acc[ 2] = fmaf(w, m0.z, acc[ 2]); acc[ 3] = fmaf(w, m0.w, acc[ 3]);
            acc[ 4] = fmaf(w, m1.x, acc[ 4]); acc[ 5] = fmaf(w, m1.y, acc[ 5]);
            acc[ 6] = fmaf(w, m1.z, acc[ 6]); acc[ 7] = fmaf(w, m1.w, acc[ 7]);
            acc[ 8] = fmaf(w, m2.x, acc[ 8]); acc[ 9] = fmaf(w, m2.y, acc[ 9]);
            acc[10] = fmaf(w, m2.z, acc[10]); acc[11] = fmaf(w, m2.w, acc[11]);
            acc[12] = fmaf(w, m3.x, acc[12]); acc[13] = fmaf(w, m3.y, acc[13]);
            acc[14] = fmaf(w, m3.z, acc[14]); acc[15] = fmaf(w, m3.w, acc[15]);
        }
    }

    // ---- wave fold-reduction: halve register count each step ----
    // Final: lane<16 holds channel brev4(lane) summed over its 64 lanes.
    const int lane = tid & 63;
    float r[16];
    #pragma unroll
    for (int c = 0; c < 16; ++c) r[c] = acc[c];

#define FOLD(MASK, HALF)                                        \
    {                                                           \
        const bool hi = (lane & (MASK)) != 0;                   \
        _Pragma("unroll")                                       \
        for (int i = 0; i < (HALF); ++i) {                      \
            const float give = hi ? r[i] : r[i + (HALF)];       \
            const float keep = hi ? r[i + (HALF)] : r[i];       \
            r[i] = keep + __shfl_xor(give, (MASK), 64);         \
        }                                                       \
    }
    FOLD(1, 8)
    FOLD(2, 4)
    FOLD(4, 2)
    FOLD(8, 1)
#undef FOLD
    float sum = r[0];
    sum += __shfl_xor(sum, 16, 64);
    sum += __shfl_xor(sum, 32, 64);
    const int l4 = lane & 15;
    const int ch = ((l4 & 1) << 3) | ((l4 & 2) << 1) | ((l4 & 4) >> 1) | ((l4 & 8) >> 3);

    // ---- cross-wave combine (4 waves) + contiguous partial store ----
    __shared__ float ws[4][16];
    if (lane < 16) ws[tid >> 6][ch] = sum;
    __syncthreads();

    if (tid < 16) {
        const float p = ws[0][tid] + ws[1][tid] + ws[2][tid] + ws[3][tid];
        part[(chunk * BRAYS + b) * 16 + tid] = p;   // 64B contiguous per block
    }
}

// part[k][b][c] summed over k -> out[b][c].
// 512 threads, one per output element; per wave-instr the 64 lanes read a
// contiguous 256B line (fully coalesced), 32 independent loads per thread.
__global__ __launch_bounds__(512)
void hpm_reduce(const float* __restrict__ part, float* __restrict__ out)
{
    const int e = threadIdx.x;          // (b*16 + c)
    float s = 0.0f;
    #pragma unroll
    for (int k = 0; k < NCHUNK; ++k)
        s += part[k * (BRAYS * 16) + e];
    out[e] = s;
}

extern "C" void kernel_launch(void* const* d_in, const int* in_sizes, int n_in,
                              void* d_out, int out_size, void* d_ws, size_t ws_size,
                              hipStream_t stream)
{
    const float* ray_o = (const float*)d_in[0];   // [32,3]
    const float* ray_d = (const float*)d_in[1];   // [32,3]
    const float* mem   = (const float*)d_in[2];   // [128^3,16]
    float* out  = (float*)d_out;                  // [32,16]
    float* part = (float*)d_ws;                   // [32][32][16] = 64 KB

    hipLaunchKernelGGL(hpm_tube, dim3(NBLK), dim3(NTHR), 0, stream,
                       ray_o, ray_d, mem, part);
    hipLaunchKernelGGL(hpm_reduce, dim3(1), dim3(512), 0, stream,
                       part, out);
}